// Round 15
// baseline (281.754 us; speedup 1.0000x reference)
//
#include <hip/hip_runtime.h>

typedef _Float16 h16;
typedef h16 half8 __attribute__((ext_vector_type(8)));
typedef h16 half4v __attribute__((ext_vector_type(4)));
typedef __fp16 fp16x2 __attribute__((ext_vector_type(2)));  // cvt_pkrtz return type
typedef float f32x4 __attribute__((ext_vector_type(4)));

#define BB 4
#define SS 2048
#define EE 1024
#define HH 16
#define DH 64

__device__ __forceinline__ void gload_lds16(const void* g, void* l) {
  __builtin_amdgcn_global_load_lds((const __attribute__((address_space(1))) void*)g,
                                   (__attribute__((address_space(3))) void*)l, 16, 0, 0);
}

// assemble 4 packed half2 dwords (cvt_pkrtz results) into a half8 fragment
__device__ __forceinline__ half8 mk8(fp16x2 a, fp16x2 b, fp16x2 c, fp16x2 d) {
  union { fp16x2 p[4]; half8 v; } u;
  u.p[0] = a; u.p[1] = b; u.p[2] = c; u.p[3] = d;
  return u.v;
}

// ---------------- mask pack: int32 -> bitmask ----------------
__global__ __launch_bounds__(256) void mha_pack_mask(const int* __restrict__ mask,
                                                     unsigned* __restrict__ maskw) {
  int gid = blockIdx.x * 256 + threadIdx.x;
  unsigned long long bal = __ballot(mask[gid] != 0);
  int lane = threadIdx.x & 63;
  if (lane == 0) maskw[gid >> 5] = (unsigned)bal;
  else if (lane == 32) maskw[gid >> 5] = (unsigned)(bal >> 32);
}

// ---------------- weight transpose + fp32->fp16 ----------------
__global__ __launch_bounds__(256) void mha_wtrans(const float* __restrict__ w0, const float* __restrict__ w1,
                                                  const float* __restrict__ w2, const float* __restrict__ w3,
                                                  h16* __restrict__ o0, h16* __restrict__ o1,
                                                  h16* __restrict__ o2, h16* __restrict__ o3) {
  __shared__ float t[32][33];
  int z = blockIdx.z;
  const float* src = z == 0 ? w0 : z == 1 ? w1 : z == 2 ? w2 : w3;
  h16* dst = z == 0 ? o0 : z == 1 ? o1 : z == 2 ? o2 : o3;
  int x = threadIdx.x, y = threadIdx.y;
  int bx = blockIdx.x * 32, by = blockIdx.y * 32;
#pragma unroll
  for (int i = 0; i < 4; ++i)
    t[y + i * 8][x] = src[(size_t)(by + y + i * 8) * EE + bx + x];
  __syncthreads();
#pragma unroll
  for (int i = 0; i < 4; ++i)
    dst[(size_t)(bx + y + i * 8) * EE + by + x] = (h16)t[x][y + i * 8];
}

// ---------------- fp32 -> fp16 bulk convert (query/key/value) ----------------
__global__ __launch_bounds__(256) void mha_cvt(const float* __restrict__ s0, const float* __restrict__ s1,
                                               const float* __restrict__ s2, h16* __restrict__ d0,
                                               h16* __restrict__ d1, h16* __restrict__ d2) {
  int z = blockIdx.z;
  const float* s = z == 0 ? s0 : z == 1 ? s1 : s2;
  h16* d = z == 0 ? d0 : z == 1 ? d1 : d2;
  size_t i = ((size_t)blockIdx.x * 256 + threadIdx.x) * 8;
  float4 a = *reinterpret_cast<const float4*>(&s[i]);
  float4 b = *reinterpret_cast<const float4*>(&s[i + 4]);
  half8 h;
  h[0] = (h16)a.x; h[1] = (h16)a.y; h[2] = (h16)a.z; h[3] = (h16)a.w;
  h[4] = (h16)b.x; h[5] = (h16)b.y; h[6] = (h16)b.z; h[7] = (h16)b.w;
  *reinterpret_cast<half8*>(&d[i]) = h;
}

// ------- QKV projection GEMM: 128x128, BK=32, dbuf (32KB LDS -> 4-5
// blocks/CU for latency hiding), XCD-swizzled. 64B rows: chunk-XOR by
// (row&3) gives the 2-way bank minimum (free). -------
#define PTM 128
#define PTN 128
#define PBK 64   /* oproj keeps BK=64 */
#define PBK2 32  /* proj BK */

__global__ __launch_bounds__(256) void mha_proj(
    const h16* __restrict__ Xq, const h16* __restrict__ Xk, const h16* __restrict__ Xv,
    const h16* __restrict__ Wqt, const h16* __restrict__ Wkt, const h16* __restrict__ Wvt,
    const float* __restrict__ bq, const float* __restrict__ bk, const float* __restrict__ bv,
    h16* __restrict__ Oq, h16* __restrict__ Ok, h16* __restrict__ Ov) {
  int z = blockIdx.z;
  const h16* X = z == 0 ? Xq : z == 1 ? Xk : Xv;
  const h16* Wt = z == 0 ? Wqt : z == 1 ? Wkt : Wvt;
  const float* bias = z == 0 ? bq : z == 1 ? bk : bv;
  h16* out = z == 0 ? Oq : z == 1 ? Ok : Ov;

  __shared__ __align__(16) h16 As[2][PTM * PBK2];
  __shared__ __align__(16) h16 Bs[2][PTN * PBK2];

  int tid = threadIdx.x;
  int lane = tid & 63, wid = tid >> 6;
  int l15 = lane & 15, l4 = lane >> 4;
  int wr = wid >> 1, wc = wid & 1;
  // T1 XCD swizzle (bijective: 512 % 8 == 0)
  int bid = blockIdx.y * 8 + blockIdx.x;
  int swz = (bid & 7) * 64 + (bid >> 3);
  int mbase = (swz >> 3) * PTM;
  int nbase = (swz & 7) * PTN;

  const f32x4 fz = {0.f, 0.f, 0.f, 0.f};
  f32x4 acc[4][4];
#pragma unroll
  for (int i = 0; i < 4; ++i)
#pragma unroll
    for (int j = 0; j < 4; ++j) acc[i][j] = fz;

  int r_loc = lane >> 2;   // 0..15 within the wave's 16-row slab
  int ch = lane & 3;       // physical 16B chunk within the 64B row

  auto STAGE = [&](int buf, int kt) {
#pragma unroll
    for (int c = 0; c < 2; ++c) {
      int row = c * 64 + wid * 16 + r_loc;
      int sc_ = ch ^ (row & 3);  // chunk-XOR swizzle via per-lane source addr
      gload_lds16(&X[(size_t)(mbase + row) * EE + kt + sc_ * 8], &As[buf][(c * 64 + wid * 16) * PBK2]);
      gload_lds16(&Wt[(size_t)(nbase + row) * EE + kt + sc_ * 8], &Bs[buf][(c * 64 + wid * 16) * PBK2]);
    }
  };

  STAGE(0, 0);
  __syncthreads();
  int cur = 0;

  for (int kt = 0; kt < EE; kt += PBK2) {
    if (kt + PBK2 < EE) STAGE(cur ^ 1, kt + PBK2);  // prefetch next K-tile

    half8 a[4], b[4];
#pragma unroll
    for (int i = 0; i < 4; ++i) {
      int ra = wr * 64 + i * 16 + l15;
      int rb = wc * 64 + i * 16 + l15;
      a[i] = *reinterpret_cast<const half8*>(&As[cur][ra * PBK2 + ((l4 ^ (ra & 3)) * 8)]);
      b[i] = *reinterpret_cast<const half8*>(&Bs[cur][rb * PBK2 + ((l4 ^ (rb & 3)) * 8)]);
    }
#pragma unroll
    for (int mi = 0; mi < 4; ++mi)
#pragma unroll
      for (int ni = 0; ni < 4; ++ni)
        acc[mi][ni] = __builtin_amdgcn_mfma_f32_16x16x32_f16(b[ni], a[mi], acc[mi][ni], 0, 0, 0);

    __syncthreads();  // drains prefetch after compute; swaps buffers
    cur ^= 1;
  }

  // acc[mi][ni]: row = n-sub (l4*4+j), col = m-sub (l15).
  const float qscale = (z == 0) ? 1.44269504088896f : 1.0f;
#pragma unroll
  for (int mi = 0; mi < 4; ++mi) {
    int m = mbase + wr * 64 + mi * 16 + l15;
    int b_ = m >> 11, s = m & 2047;
#pragma unroll
    for (int ni = 0; ni < 4; ++ni) {
      int n0 = nbase + wc * 64 + ni * 16 + l4 * 4;
      int h = n0 >> 6, d0 = n0 & 63;
      float4 b4 = *reinterpret_cast<const float4*>(&bias[n0]);
      if (z != 2) {
        half4v w;
        w[0] = (h16)((acc[mi][ni][0] + b4.x) * qscale);
        w[1] = (h16)((acc[mi][ni][1] + b4.y) * qscale);
        w[2] = (h16)((acc[mi][ni][2] + b4.z) * qscale);
        w[3] = (h16)((acc[mi][ni][3] + b4.w) * qscale);
        *reinterpret_cast<half4v*>(&out[(((size_t)(b_ * HH + h)) * SS + s) * DH + d0]) = w;  // (B,H,S,D)
      } else {
#pragma unroll
        for (int j = 0; j < 4; ++j)  // V^T (B,H,D,S): lanes coalesced along s
          out[(((size_t)(b_ * HH + h)) * DH + d0 + j) * SS + s] = (h16)(acc[mi][ni][j] + b4[j]);
      }
    }
  }
}

// ---------------- flash attention (frozen: R10/R13 structure) ----------------
__global__ __launch_bounds__(256) void mha_attn(
    const h16* __restrict__ qh, const h16* __restrict__ kh, const h16* __restrict__ vh,
    const unsigned* __restrict__ maskw, h16* __restrict__ ah) {
  __shared__ __align__(16) h16 Ks[2][64 * 64];
  __shared__ __align__(16) h16 Vs[2][64 * 64];

  int bh = blockIdx.y;
  int b_ = bh >> 4, hh = bh & 15;
  int tid = threadIdx.x, lane = tid & 63, wid = tid >> 6;
  int l15 = lane & 15, l4 = lane >> 4;

  const h16* Qb = qh + (size_t)bh * SS * DH;
  const h16* Kb = kh + (size_t)bh * SS * DH;
  const h16* Vb = vh + (size_t)bh * DH * SS;
  int qrow0 = blockIdx.x * 128 + wid * 32;

  // Q fragments (B-operand of 16x16x32): lane holds Q[q = l15][k = l4*8..]
  half8 qf[2][2];
#pragma unroll
  for (int mi = 0; mi < 2; ++mi)
#pragma unroll
    for (int kk = 0; kk < 2; ++kk)
      qf[mi][kk] = *reinterpret_cast<const half8*>(&Qb[(size_t)(qrow0 + mi * 16 + l15) * DH + kk * 32 + l4 * 8]);

  half8 ones;
#pragma unroll
  for (int e = 0; e < 8; ++e) ones[e] = (h16)1.0f;

  float m_run[2] = {-1e30f, -1e30f};
  f32x4 l_acc[2];
  f32x4 oacc[2][4];
  const f32x4 fz = {0.f, 0.f, 0.f, 0.f};
#pragma unroll
  for (int mi = 0; mi < 2; ++mi) {
    l_acc[mi] = fz;
#pragma unroll
    for (int di = 0; di < 4; ++di) oacc[mi][di] = fz;
  }

  const unsigned* mwb = maskw + ((size_t)b_ * SS + qrow0) * 64;
  const unsigned* mrow0 = mwb + l15 * 64;
  const unsigned* mrow1 = mwb + (16 + l15) * 64;

  int srow = wid * 16 + (lane >> 3);   // physical LDS row this lane stages
  int schunk = lane & 7;
  int sh0 = l4 * 8;  // mask bit base: logical t = 8*l4 + 4*(ni&1) + j

  // staging sources (K rows permuted; XOR-swizzled chunks)
  int rp0 = srow, rp1 = srow + 8;
  int rl0 = (rp0 & 32) + ((rp0 >> 2) & 3) * 8 + ((rp0 >> 4) & 1) * 4 + (rp0 & 3);
  int rl1 = (rp1 & 32) + ((rp1 >> 2) & 3) * 8 + ((rp1 >> 4) & 1) * 4 + (rp1 & 3);
  int gk0 = schunk ^ (rp0 & 7), gk1 = schunk ^ (rp1 & 7);
  const h16* kp0 = Kb + (size_t)rl0 * DH + gk0 * 8;
  const h16* kp1 = Kb + (size_t)rl1 * DH + gk1 * 8;
  const h16* vp0 = Vb + (size_t)rp0 * SS + gk0 * 8;
  const h16* vp1 = Vb + (size_t)rp1 * SS + gk1 * 8;

  // collapsed LDS read offsets: K and V share them (off0: kb=0, off1: kb=1)
  int sw = l15 & 7;
  int off0 = l15 * 64 + (l4 ^ sw) * 8;
  int off1 = l15 * 64 + ((l4 + 4) ^ sw) * 8;

  // prologue: stage tile 0 + its mask words
  gload_lds16(kp0, &Ks[0][wid * 1024]);
  gload_lds16(vp0, &Vs[0][wid * 1024]);
  gload_lds16(kp1, &Ks[0][wid * 1024 + 512]);
  gload_lds16(vp1, &Vs[0][wid * 1024 + 512]);
  unsigned mw[2][2];
  mw[0][0] = mrow0[0];
  mw[0][1] = mrow0[1];
  mw[1][0] = mrow1[0];
  mw[1][1] = mrow1[1];
  __syncthreads();

  // Masked logits forced to NEG before the max so m tracks the UNMASKED max;
  // exp2(-1e5 - m) == 0 exactly -> masked p contribute 0 to PV and l.
  const unsigned negb = __float_as_uint(-1e5f);

  auto TILE = [&](int itC, int tt) {
    const int itP = itC ^ 1;
    // prefetch next tile (double buffer) + next mask words
    unsigned mwn[2][2] = {{0u, 0u}, {0u, 0u}};
    if (tt + 64 < SS) {
      size_t ko = (size_t)(tt + 64) * DH;
      gload_lds16(kp0 + ko, &Ks[itP][wid * 1024]);
      gload_lds16(vp0 + tt + 64, &Vs[itP][wid * 1024]);
      gload_lds16(kp1 + ko, &Ks[itP][wid * 1024 + 512]);
      gload_lds16(vp1 + tt + 64, &Vs[itP][wid * 1024 + 512]);
      int tw = (tt + 64) >> 5;
      mwn[0][0] = mrow0[tw];
      mwn[0][1] = mrow0[tw + 1];
      mwn[1][0] = mrow1[tw];
      mwn[1][1] = mrow1[tw + 1];
    }

    // QK^T, swapped operands: st[mi][ni] rows = PHYSICAL t-rows, col = q
    half8 kf[4][2];
#pragma unroll
    for (int ni = 0; ni < 4; ++ni) {
      kf[ni][0] = *reinterpret_cast<const half8*>(&Ks[itC][off0 + ni * 1024]);
      kf[ni][1] = *reinterpret_cast<const half8*>(&Ks[itC][off1 + ni * 1024]);
    }
    f32x4 st[2][4];
    __builtin_amdgcn_s_setprio(1);
#pragma unroll
    for (int mi = 0; mi < 2; ++mi)
#pragma unroll
      for (int ni = 0; ni < 4; ++ni) {
        f32x4 t_ = fz;
        t_ = __builtin_amdgcn_mfma_f32_16x16x32_f16(kf[ni][0], qf[mi][0], t_, 0, 0, 0);
        t_ = __builtin_amdgcn_mfma_f32_16x16x32_f16(kf[ni][1], qf[mi][1], t_, 0, 0, 0);
        st[mi][ni] = t_;
      }
    __builtin_amdgcn_s_setprio(0);

    // V fragments (A-operand of x32): V[d=di*16+l15][t=32kb+l4*8+e]
    half8 vf[4][2];
#pragma unroll
    for (int di = 0; di < 4; ++di) {
      vf[di][0] = *reinterpret_cast<const half8*>(&Vs[itC][off0 + di * 1024]);
      vf[di][1] = *reinterpret_cast<const half8*>(&Vs[itC][off1 + di * 1024]);
    }

    // mask BEFORE max: logical t = 32*(ni>>1) + 8*l4 + 4*(ni&1) + j
#pragma unroll
    for (int mi = 0; mi < 2; ++mi) {
#pragma unroll
      for (int ni = 0; ni < 4; ++ni) {
        unsigned m4 = mw[mi][ni >> 1] >> (sh0 + 4 * (ni & 1));
#pragma unroll
        for (int j = 0; j < 4; ++j) {
          unsigned sel = (unsigned)(((int)(m4 << (31 - j))) >> 31);  // 0 or ~0
          st[mi][ni][j] = __uint_as_float((~sel & __float_as_uint(st[mi][ni][j])) | (sel & negb));
        }
      }
    }

    // online softmax, log2 domain
    half8 pfrag[2][2];
#pragma unroll
    for (int mi = 0; mi < 2; ++mi) {
      float t0 = fmaxf(fmaxf(st[mi][0][0], st[mi][0][1]), st[mi][0][2]);
      float t1 = fmaxf(fmaxf(st[mi][0][3], st[mi][1][0]), st[mi][1][1]);
      float t2 = fmaxf(fmaxf(st[mi][1][2], st[mi][1][3]), st[mi][2][0]);
      float t3 = fmaxf(fmaxf(st[mi][2][1], st[mi][2][2]), st[mi][2][3]);
      float t4 = fmaxf(fmaxf(st[mi][3][0], st[mi][3][1]), st[mi][3][2]);
      float tmax = fmaxf(fmaxf(fmaxf(t0, t1), fmaxf(t2, t3)), fmaxf(t4, st[mi][3][3]));
      tmax = fmaxf(tmax, __shfl_xor(tmax, 16));
      tmax = fmaxf(tmax, __shfl_xor(tmax, 32));
      // T13 defer-max: rescale only when max grew by > 8 (2^8 headroom in f16)
      if (!__all(tmax - m_run[mi] <= 8.0f)) {
        float mnew = fmaxf(m_run[mi], tmax);
        float sc = __builtin_amdgcn_exp2f(m_run[mi] - mnew);
        l_acc[mi][0] *= sc;  // only component 0 is read at the end
#pragma unroll
        for (int di = 0; di < 4; ++di) oacc[mi][di] *= sc;
        m_run[mi] = mnew;
      }
      float mneg = -m_run[mi];
#pragma unroll
      for (int ni = 0; ni < 4; ++ni)
#pragma unroll
        for (int j = 0; j < 4; ++j)
          st[mi][ni][j] = __builtin_amdgcn_exp2f(st[mi][ni][j] + mneg);
      // pack P in registers (dword-level; concat quads == x32 B-fragment)
#pragma unroll
      for (int kb = 0; kb < 2; ++kb) {
        pfrag[mi][kb] = mk8(__builtin_amdgcn_cvt_pkrtz(st[mi][2 * kb][0], st[mi][2 * kb][1]),
                            __builtin_amdgcn_cvt_pkrtz(st[mi][2 * kb][2], st[mi][2 * kb][3]),
                            __builtin_amdgcn_cvt_pkrtz(st[mi][2 * kb + 1][0], st[mi][2 * kb + 1][1]),
                            __builtin_amdgcn_cvt_pkrtz(st[mi][2 * kb + 1][2], st[mi][2 * kb + 1][3]));
      }
    }

    // PV + l-row: full-rate x32 MFMAs, P straight from registers
    __builtin_amdgcn_s_setprio(1);
#pragma unroll
    for (int mi = 0; mi < 2; ++mi) {
#pragma unroll
      for (int di = 0; di < 4; ++di) {
        oacc[mi][di] = __builtin_amdgcn_mfma_f32_16x16x32_f16(vf[di][0], pfrag[mi][0], oacc[mi][di], 0, 0, 0);
        oacc[mi][di] = __builtin_amdgcn_mfma_f32_16x16x32_f16(vf[di][1], pfrag[mi][1], oacc[mi][di], 0, 0, 0);
      }
      l_acc[mi] = __builtin_amdgcn_mfma_f32_16x16x32_f16(ones, pfrag[mi][0], l_acc[mi], 0, 0, 0);
      l_acc[mi] = __builtin_amdgcn_mfma_f32_16x16x32_f16(ones, pfrag[mi][1], l_acc[mi], 0, 0, 0);
    }
    __builtin_amdgcn_s_setprio(0);

    mw[0][0] = mwn[0][0]; mw[0][1] = mwn[0][1];
    mw[1][0] = mwn[1][0]; mw[1][1] = mwn[1][1];
    __syncthreads();
  };

  for (int tt = 0; tt < SS; tt += 128) {  // unroll-2: compile-time buffers
    TILE(0, tt);
    TILE(1, tt + 64);
  }

  // epilogue: /= (l * sqrt(64)); lane owns q = mi*16+l15, d = di*16+l4*4+j
#pragma unroll
  for (int mi = 0; mi < 2; ++mi) {
    float inv = 1.f / (l_acc[mi][0] * 8.f);
    size_t rowb = ((size_t)b_ * SS + (qrow0 + mi * 16 + l15)) * EE + hh * DH;
#pragma unroll
    for (int di = 0; di < 4; ++di) {
      half4v w;
#pragma unroll
      for (int j = 0; j < 4; ++j) w[j] = (h16)(oacc[mi][di][j] * inv);
      *reinterpret_cast<half4v*>(&ah[rowb + di * 16 + l4 * 4]) = w;
    }
  }
}

// ------- output projection GEMM: 128x128, BK=64, dbuf, XCD-swizzled (control) -------
__global__ __launch_bounds__(256) void mha_oproj(
    const h16* __restrict__ A, const h16* __restrict__ Wot,
    const float* __restrict__ bo, float* __restrict__ out) {
  __shared__ __align__(16) h16 As[2][PTM * PBK];
  __shared__ __align__(16) h16 Bs[2][PTN * PBK];
  int tid = threadIdx.x, lane = tid & 63, wid = tid >> 6;
  int l15 = lane & 15, l4 = lane >> 4;
  int wr = wid >> 1, wc = wid & 1;
  int bid = blockIdx.y * 8 + blockIdx.x;
  int swz = (bid & 7) * 64 + (bid >> 3);
  int mbase = (swz >> 3) * PTM;
  int nbase = (swz & 7) * PTN;
  const f32x4 fz = {0.f, 0.f, 0.f, 0.f};
  f32x4 acc[4][4];
#pragma unroll
  for (int i = 0; i < 4; ++i)
#pragma unroll
    for (int j = 0; j < 4; ++j) acc[i][j] = fz;

  int r_loc = lane >> 3, ch = lane & 7;

  auto STAGE = [&](int buf, int kt) {
#pragma unroll
    for (int c = 0; c < 4; ++c) {
      int row = c * 32 + wid * 8 + r_loc;
      int sc_ = ch ^ (row & 7);
      gload_lds16(&A[(size_t)(mbase + row) * EE + kt + sc_ * 8], &As[buf][(c * 32 + wid * 8) * PBK]);
      gload_lds16(&Wot[(size_t)(nbase + row) * EE + kt + sc_ * 8], &Bs[buf][(c * 32 + wid * 8) * PBK]);
    }
  };

  STAGE(0, 0);
  __syncthreads();
  int cur = 0;

  for (int kt = 0; kt < EE; kt += PBK) {
    if (kt + PBK < EE) STAGE(cur ^ 1, kt + PBK);

    half8 a[2][4], b[2][4];
#pragma unroll
    for (int i = 0; i < 4; ++i) {
      int ra = wr * 64 + i * 16 + l15;
      int rb = wc * 64 + i * 16 + l15;
#pragma unroll
      for (int kk = 0; kk < 2; ++kk) {
        a[kk][i] = *reinterpret_cast<const half8*>(&As[cur][ra * PBK + ((kk * 4 + l4) ^ (ra & 7)) * 8]);
        b[kk][i] = *reinterpret_cast<const half8*>(&Bs[cur][rb * PBK + ((kk * 4 + l4) ^ (rb & 7)) * 8]);
      }
    }
#pragma unroll
    for (int kk = 0; kk < 2; ++kk)
#pragma unroll
      for (int mi = 0; mi < 4; ++mi)
#pragma unroll
        for (int ni = 0; ni < 4; ++ni)
          acc[mi][ni] = __builtin_amdgcn_mfma_f32_16x16x32_f16(b[kk][ni], a[kk][mi], acc[mi][ni], 0, 0, 0);

    __syncthreads();
    cur ^= 1;
  }
  // acc[mi][ni]: row = n-sub (l4*4+j), col = m-sub (l15) -> float4 stores
#pragma unroll
  for (int mi = 0; mi < 4; ++mi) {
    int m = mbase + wr * 64 + mi * 16 + l15;
#pragma unroll
    for (int ni = 0; ni < 4; ++ni) {
      int n0 = nbase + wc * 64 + ni * 16 + l4 * 4;
      float4 b4 = *reinterpret_cast<const float4*>(&bo[n0]);
      float4 w;
      w.x = acc[mi][ni][0] + b4.x;
      w.y = acc[mi][ni][1] + b4.y;
      w.z = acc[mi][ni][2] + b4.z;
      w.w = acc[mi][ni][3] + b4.w;
      *reinterpret_cast<float4*>(&out[(size_t)m * EE + n0]) = w;
    }
  }
}

extern "C" void kernel_launch(void* const* d_in, const int* in_sizes, int n_in,
                              void* d_out, int out_size, void* d_ws, size_t ws_size,
                              hipStream_t stream) {
  const float* query = (const float*)d_in[0];
  const float* key_ = (const float*)d_in[1];
  const float* value = (const float*)d_in[2];
  const int* mask = (const int*)d_in[3];
  const float* Wq = (const float*)d_in[4];
  const float* bq = (const float*)d_in[5];
  const float* Wk = (const float*)d_in[6];
  const float* bk = (const float*)d_in[7];
  const float* Wv = (const float*)d_in[8];
  const float* bv = (const float*)d_in[9];
  const float* Wo = (const float*)d_in[10];
  const float* bo = (const float*)d_in[11];
  float* out = (float*)d_out;

  const size_t MH = 1u << 20;                  // halves per 1024x1024 weight
  const size_t QH = (size_t)BB * HH * SS * DH; // 8388608 halves
  h16* wqt = (h16*)d_ws;
  h16* wkt = wqt + MH;
  h16* wvt = wkt + MH;
  h16* wot = wvt + MH;
  h16* qh = wot + MH;
  h16* kh = qh + QH;
  h16* vh = kh + QH;
  h16* ah = vh + QH;
  unsigned* maskw = (unsigned*)(ah + QH);

  // f16 input scratch: xq aliases the ah slot (dead before attn writes ah);
  // xk/xv live inside d_out (exactly 2*QH halves; dead until oproj overwrites).
  h16* xq = ah;
  h16* xk = (h16*)d_out;
  h16* xv = xk + QH;

  mha_pack_mask<<<(BB * SS * SS) / 256, 256, 0, stream>>>(mask, maskw);
  mha_wtrans<<<dim3(32, 32, 4), dim3(32, 8), 0, stream>>>(Wq, Wk, Wv, Wo, wqt, wkt, wvt, wot);
  mha_cvt<<<dim3((BB * SS * EE) / 2048, 1, 3), 256, 0, stream>>>(query, key_, value, xq, xk, xv);
  mha_proj<<<dim3(EE / PTN, (BB * SS) / PTM, 3), 256, 0, stream>>>(
      xq, xk, xv, wqt, wkt, wvt, bq, bk, bv, qh, kh, vh);
  mha_attn<<<dim3(SS / 128, BB * HH), 256, 0, stream>>>(qh, kh, vh, maskw, ah);
  mha_oproj<<<dim3(EE / PTN, (BB * SS) / PTM), 256, 0, stream>>>(ah, wot, bo, out);
}

// Round 16
// 269.145 us; speedup vs baseline: 1.0468x; 1.0468x over previous
//
#include <hip/hip_runtime.h>

typedef _Float16 h16;
typedef h16 half8 __attribute__((ext_vector_type(8)));
typedef h16 half4v __attribute__((ext_vector_type(4)));
typedef __fp16 fp16x2 __attribute__((ext_vector_type(2)));  // cvt_pkrtz return type
typedef float f32x4 __attribute__((ext_vector_type(4)));

#define BB 4
#define SS 2048
#define EE 1024
#define HH 16
#define DH 64

__device__ __forceinline__ void gload_lds16(const void* g, void* l) {
  __builtin_amdgcn_global_load_lds((const __attribute__((address_space(1))) void*)g,
                                   (__attribute__((address_space(3))) void*)l, 16, 0, 0);
}

// assemble 4 packed half2 dwords (cvt_pkrtz results) into a half8 fragment
__device__ __forceinline__ half8 mk8(fp16x2 a, fp16x2 b, fp16x2 c, fp16x2 d) {
  union { fp16x2 p[4]; half8 v; } u;
  u.p[0] = a; u.p[1] = b; u.p[2] = c; u.p[3] = d;
  return u.v;
}

// ---- merged prep: mask pack (65536 blocks) + fp32->f16 cvt (12288) +
// weight transpose (4096). Branch is uniform per block. ----
__global__ __launch_bounds__(256) void mha_prep(
    const int* __restrict__ mask, unsigned* __restrict__ maskw,
    const float* __restrict__ q, const float* __restrict__ k, const float* __restrict__ v,
    h16* __restrict__ xq, h16* __restrict__ xk, h16* __restrict__ xv,
    const float* __restrict__ w0, const float* __restrict__ w1,
    const float* __restrict__ w2, const float* __restrict__ w3,
    h16* __restrict__ o0, h16* __restrict__ o1, h16* __restrict__ o2, h16* __restrict__ o3) {
  __shared__ float t[32][33];
  int bid = blockIdx.x;
  int tid = threadIdx.x;
  if (bid < 65536) {
    // mask pack: int32 -> bitmask
    int gid = bid * 256 + tid;
    unsigned long long bal = __ballot(mask[gid] != 0);
    int lane = tid & 63;
    if (lane == 0) maskw[gid >> 5] = (unsigned)bal;
    else if (lane == 32) maskw[gid >> 5] = (unsigned)(bal >> 32);
  } else if (bid < 65536 + 12288) {
    // fp32 -> fp16 bulk convert (query/key/value)
    int idx = bid - 65536;
    int z = idx >> 12;          // / 4096
    int xb = idx & 4095;
    const float* s = z == 0 ? q : z == 1 ? k : v;
    h16* d = z == 0 ? xq : z == 1 ? xk : xv;
    size_t i = ((size_t)xb * 256 + tid) * 8;
    float4 a = *reinterpret_cast<const float4*>(&s[i]);
    float4 b = *reinterpret_cast<const float4*>(&s[i + 4]);
    half8 h;
    h[0] = (h16)a.x; h[1] = (h16)a.y; h[2] = (h16)a.z; h[3] = (h16)a.w;
    h[4] = (h16)b.x; h[5] = (h16)b.y; h[6] = (h16)b.z; h[7] = (h16)b.w;
    *reinterpret_cast<half8*>(&d[i]) = h;
  } else {
    // weight transpose + fp32->fp16
    int idx = bid - (65536 + 12288);
    int z = idx >> 10;          // / 1024
    int rem = idx & 1023;
    const float* src = z == 0 ? w0 : z == 1 ? w1 : z == 2 ? w2 : w3;
    h16* dst = z == 0 ? o0 : z == 1 ? o1 : z == 2 ? o2 : o3;
    int x = tid & 31, y = tid >> 5;         // (32, 8) thread layout
    int bx = (rem & 31) * 32, by = (rem >> 5) * 32;
#pragma unroll
    for (int i = 0; i < 4; ++i)
      t[y + i * 8][x] = src[(size_t)(by + y + i * 8) * EE + bx + x];
    __syncthreads();
#pragma unroll
    for (int i = 0; i < 4; ++i)
      dst[(size_t)(bx + y + i * 8) * EE + by + x] = (h16)t[x][y + i * 8];
  }
}

// ------- QKV projection GEMM: 128x128, BK=64, dbuf, XCD-swizzled -------
#define PTM 128
#define PTN 128
#define PBK 64

__global__ __launch_bounds__(256) void mha_proj(
    const h16* __restrict__ Xq, const h16* __restrict__ Xk, const h16* __restrict__ Xv,
    const h16* __restrict__ Wqt, const h16* __restrict__ Wkt, const h16* __restrict__ Wvt,
    const float* __restrict__ bq, const float* __restrict__ bk, const float* __restrict__ bv,
    h16* __restrict__ Oq, h16* __restrict__ Ok, h16* __restrict__ Ov) {
  int z = blockIdx.z;
  const h16* X = z == 0 ? Xq : z == 1 ? Xk : Xv;
  const h16* Wt = z == 0 ? Wqt : z == 1 ? Wkt : Wvt;
  const float* bias = z == 0 ? bq : z == 1 ? bk : bv;
  h16* out = z == 0 ? Oq : z == 1 ? Ok : Ov;

  __shared__ __align__(16) h16 As[2][PTM * PBK];
  __shared__ __align__(16) h16 Bs[2][PTN * PBK];

  int tid = threadIdx.x;
  int lane = tid & 63, wid = tid >> 6;
  int l15 = lane & 15, l4 = lane >> 4;
  int wr = wid >> 1, wc = wid & 1;
  // T1 XCD swizzle (bijective: 512 % 8 == 0)
  int bid = blockIdx.y * 8 + blockIdx.x;
  int swz = (bid & 7) * 64 + (bid >> 3);
  int mbase = (swz >> 3) * PTM;
  int nbase = (swz & 7) * PTN;

  const f32x4 fz = {0.f, 0.f, 0.f, 0.f};
  f32x4 acc[4][4];
#pragma unroll
  for (int i = 0; i < 4; ++i)
#pragma unroll
    for (int j = 0; j < 4; ++j) acc[i][j] = fz;

  int r_loc = lane >> 3;   // 0..7 within the wave's 8-row slab
  int ch = lane & 7;       // physical 16B chunk within the 128B row

  auto STAGE = [&](int buf, int kt) {
#pragma unroll
    for (int c = 0; c < 4; ++c) {
      int row = c * 32 + wid * 8 + r_loc;
      int sc_ = ch ^ (row & 7);  // chunk-XOR swizzle via per-lane source addr
      gload_lds16(&X[(size_t)(mbase + row) * EE + kt + sc_ * 8], &As[buf][(c * 32 + wid * 8) * PBK]);
      gload_lds16(&Wt[(size_t)(nbase + row) * EE + kt + sc_ * 8], &Bs[buf][(c * 32 + wid * 8) * PBK]);
    }
  };

  STAGE(0, 0);
  __syncthreads();
  int cur = 0;

  for (int kt = 0; kt < EE; kt += PBK) {
    if (kt + PBK < EE) STAGE(cur ^ 1, kt + PBK);  // prefetch next K-tile

    half8 a[2][4], b[2][4];
#pragma unroll
    for (int i = 0; i < 4; ++i) {
      int ra = wr * 64 + i * 16 + l15;
      int rb = wc * 64 + i * 16 + l15;
#pragma unroll
      for (int kk = 0; kk < 2; ++kk) {
        a[kk][i] = *reinterpret_cast<const half8*>(&As[cur][ra * PBK + ((kk * 4 + l4) ^ (ra & 7)) * 8]);
        b[kk][i] = *reinterpret_cast<const half8*>(&Bs[cur][rb * PBK + ((kk * 4 + l4) ^ (rb & 7)) * 8]);
      }
    }
#pragma unroll
    for (int kk = 0; kk < 2; ++kk)
#pragma unroll
      for (int mi = 0; mi < 4; ++mi)
#pragma unroll
        for (int ni = 0; ni < 4; ++ni)
          acc[mi][ni] = __builtin_amdgcn_mfma_f32_16x16x32_f16(b[kk][ni], a[kk][mi], acc[mi][ni], 0, 0, 0);

    __syncthreads();  // drains prefetch after compute; swaps buffers
    cur ^= 1;
  }

  // acc[mi][ni]: row = n-sub (l4*4+j), col = m-sub (l15).
  const float qscale = (z == 0) ? 1.44269504088896f : 1.0f;
#pragma unroll
  for (int mi = 0; mi < 4; ++mi) {
    int m = mbase + wr * 64 + mi * 16 + l15;
    int b_ = m >> 11, s = m & 2047;
#pragma unroll
    for (int ni = 0; ni < 4; ++ni) {
      int n0 = nbase + wc * 64 + ni * 16 + l4 * 4;
      int h = n0 >> 6, d0 = n0 & 63;
      float4 b4 = *reinterpret_cast<const float4*>(&bias[n0]);
      if (z != 2) {
        half4v w;
        w[0] = (h16)((acc[mi][ni][0] + b4.x) * qscale);
        w[1] = (h16)((acc[mi][ni][1] + b4.y) * qscale);
        w[2] = (h16)((acc[mi][ni][2] + b4.z) * qscale);
        w[3] = (h16)((acc[mi][ni][3] + b4.w) * qscale);
        *reinterpret_cast<half4v*>(&out[(((size_t)(b_ * HH + h)) * SS + s) * DH + d0]) = w;  // (B,H,S,D)
      } else {
#pragma unroll
        for (int j = 0; j < 4; ++j)  // V^T (B,H,D,S): lanes coalesced along s
          out[(((size_t)(b_ * HH + h)) * DH + d0 + j) * SS + s] = (h16)(acc[mi][ni][j] + b4[j]);
      }
    }
  }
}

// ---------------- flash attention (frozen: R10/R13 structure) ----------------
__global__ __launch_bounds__(256) void mha_attn(
    const h16* __restrict__ qh, const h16* __restrict__ kh, const h16* __restrict__ vh,
    const unsigned* __restrict__ maskw, h16* __restrict__ ah) {
  __shared__ __align__(16) h16 Ks[2][64 * 64];
  __shared__ __align__(16) h16 Vs[2][64 * 64];

  int bh = blockIdx.y;
  int b_ = bh >> 4, hh = bh & 15;
  int tid = threadIdx.x, lane = tid & 63, wid = tid >> 6;
  int l15 = lane & 15, l4 = lane >> 4;

  const h16* Qb = qh + (size_t)bh * SS * DH;
  const h16* Kb = kh + (size_t)bh * SS * DH;
  const h16* Vb = vh + (size_t)bh * DH * SS;
  int qrow0 = blockIdx.x * 128 + wid * 32;

  // Q fragments (B-operand of 16x16x32): lane holds Q[q = l15][k = l4*8..]
  half8 qf[2][2];
#pragma unroll
  for (int mi = 0; mi < 2; ++mi)
#pragma unroll
    for (int kk = 0; kk < 2; ++kk)
      qf[mi][kk] = *reinterpret_cast<const half8*>(&Qb[(size_t)(qrow0 + mi * 16 + l15) * DH + kk * 32 + l4 * 8]);

  half8 ones;
#pragma unroll
  for (int e = 0; e < 8; ++e) ones[e] = (h16)1.0f;

  float m_run[2] = {-1e30f, -1e30f};
  f32x4 l_acc[2];
  f32x4 oacc[2][4];
  const f32x4 fz = {0.f, 0.f, 0.f, 0.f};
#pragma unroll
  for (int mi = 0; mi < 2; ++mi) {
    l_acc[mi] = fz;
#pragma unroll
    for (int di = 0; di < 4; ++di) oacc[mi][di] = fz;
  }

  const unsigned* mwb = maskw + ((size_t)b_ * SS + qrow0) * 64;
  const unsigned* mrow0 = mwb + l15 * 64;
  const unsigned* mrow1 = mwb + (16 + l15) * 64;

  int srow = wid * 16 + (lane >> 3);   // physical LDS row this lane stages
  int schunk = lane & 7;
  int sh0 = l4 * 8;  // mask bit base: logical t = 8*l4 + 4*(ni&1) + j

  // staging sources (K rows permuted; XOR-swizzled chunks)
  int rp0 = srow, rp1 = srow + 8;
  int rl0 = (rp0 & 32) + ((rp0 >> 2) & 3) * 8 + ((rp0 >> 4) & 1) * 4 + (rp0 & 3);
  int rl1 = (rp1 & 32) + ((rp1 >> 2) & 3) * 8 + ((rp1 >> 4) & 1) * 4 + (rp1 & 3);
  int gk0 = schunk ^ (rp0 & 7), gk1 = schunk ^ (rp1 & 7);
  const h16* kp0 = Kb + (size_t)rl0 * DH + gk0 * 8;
  const h16* kp1 = Kb + (size_t)rl1 * DH + gk1 * 8;
  const h16* vp0 = Vb + (size_t)rp0 * SS + gk0 * 8;
  const h16* vp1 = Vb + (size_t)rp1 * SS + gk1 * 8;

  // collapsed LDS read offsets: K and V share them (off0: kb=0, off1: kb=1)
  int sw = l15 & 7;
  int off0 = l15 * 64 + (l4 ^ sw) * 8;
  int off1 = l15 * 64 + ((l4 + 4) ^ sw) * 8;

  // prologue: stage tile 0 + its mask words
  gload_lds16(kp0, &Ks[0][wid * 1024]);
  gload_lds16(vp0, &Vs[0][wid * 1024]);
  gload_lds16(kp1, &Ks[0][wid * 1024 + 512]);
  gload_lds16(vp1, &Vs[0][wid * 1024 + 512]);
  unsigned mw[2][2];
  mw[0][0] = mrow0[0];
  mw[0][1] = mrow0[1];
  mw[1][0] = mrow1[0];
  mw[1][1] = mrow1[1];
  __syncthreads();

  // Masked logits forced to NEG before the max so m tracks the UNMASKED max;
  // exp2(-1e5 - m) == 0 exactly -> masked p contribute 0 to PV and l.
  const unsigned negb = __float_as_uint(-1e5f);

  auto TILE = [&](int itC, int tt) {
    const int itP = itC ^ 1;
    // prefetch next tile (double buffer) + next mask words
    unsigned mwn[2][2] = {{0u, 0u}, {0u, 0u}};
    if (tt + 64 < SS) {
      size_t ko = (size_t)(tt + 64) * DH;
      gload_lds16(kp0 + ko, &Ks[itP][wid * 1024]);
      gload_lds16(vp0 + tt + 64, &Vs[itP][wid * 1024]);
      gload_lds16(kp1 + ko, &Ks[itP][wid * 1024 + 512]);
      gload_lds16(vp1 + tt + 64, &Vs[itP][wid * 1024 + 512]);
      int tw = (tt + 64) >> 5;
      mwn[0][0] = mrow0[tw];
      mwn[0][1] = mrow0[tw + 1];
      mwn[1][0] = mrow1[tw];
      mwn[1][1] = mrow1[tw + 1];
    }

    // QK^T, swapped operands: st[mi][ni] rows = PHYSICAL t-rows, col = q
    half8 kf[4][2];
#pragma unroll
    for (int ni = 0; ni < 4; ++ni) {
      kf[ni][0] = *reinterpret_cast<const half8*>(&Ks[itC][off0 + ni * 1024]);
      kf[ni][1] = *reinterpret_cast<const half8*>(&Ks[itC][off1 + ni * 1024]);
    }
    f32x4 st[2][4];
    __builtin_amdgcn_s_setprio(1);
#pragma unroll
    for (int mi = 0; mi < 2; ++mi)
#pragma unroll
      for (int ni = 0; ni < 4; ++ni) {
        f32x4 t_ = fz;
        t_ = __builtin_amdgcn_mfma_f32_16x16x32_f16(kf[ni][0], qf[mi][0], t_, 0, 0, 0);
        t_ = __builtin_amdgcn_mfma_f32_16x16x32_f16(kf[ni][1], qf[mi][1], t_, 0, 0, 0);
        st[mi][ni] = t_;
      }
    __builtin_amdgcn_s_setprio(0);

    // V fragments (A-operand of x32): V[d=di*16+l15][t=32kb+l4*8+e]
    half8 vf[4][2];
#pragma unroll
    for (int di = 0; di < 4; ++di) {
      vf[di][0] = *reinterpret_cast<const half8*>(&Vs[itC][off0 + di * 1024]);
      vf[di][1] = *reinterpret_cast<const half8*>(&Vs[itC][off1 + di * 1024]);
    }

    // mask BEFORE max: logical t = 32*(ni>>1) + 8*l4 + 4*(ni&1) + j
#pragma unroll
    for (int mi = 0; mi < 2; ++mi) {
#pragma unroll
      for (int ni = 0; ni < 4; ++ni) {
        unsigned m4 = mw[mi][ni >> 1] >> (sh0 + 4 * (ni & 1));
#pragma unroll
        for (int j = 0; j < 4; ++j) {
          unsigned sel = (unsigned)(((int)(m4 << (31 - j))) >> 31);  // 0 or ~0
          st[mi][ni][j] = __uint_as_float((~sel & __float_as_uint(st[mi][ni][j])) | (sel & negb));
        }
      }
    }

    // online softmax, log2 domain
    half8 pfrag[2][2];
#pragma unroll
    for (int mi = 0; mi < 2; ++mi) {
      float t0 = fmaxf(fmaxf(st[mi][0][0], st[mi][0][1]), st[mi][0][2]);
      float t1 = fmaxf(fmaxf(st[mi][0][3], st[mi][1][0]), st[mi][1][1]);
      float t2 = fmaxf(fmaxf(st[mi][1][2], st[mi][1][3]), st[mi][2][0]);
      float t3 = fmaxf(fmaxf(st[mi][2][1], st[mi][2][2]), st[mi][2][3]);
      float t4 = fmaxf(fmaxf(st[mi][3][0], st[mi][3][1]), st[mi][3][2]);
      float tmax = fmaxf(fmaxf(fmaxf(t0, t1), fmaxf(t2, t3)), fmaxf(t4, st[mi][3][3]));
      tmax = fmaxf(tmax, __shfl_xor(tmax, 16));
      tmax = fmaxf(tmax, __shfl_xor(tmax, 32));
      // T13 defer-max: rescale only when max grew by > 8 (2^8 headroom in f16)
      if (!__all(tmax - m_run[mi] <= 8.0f)) {
        float mnew = fmaxf(m_run[mi], tmax);
        float sc = __builtin_amdgcn_exp2f(m_run[mi] - mnew);
        l_acc[mi][0] *= sc;  // only component 0 is read at the end
#pragma unroll
        for (int di = 0; di < 4; ++di) oacc[mi][di] *= sc;
        m_run[mi] = mnew;
      }
      float mneg = -m_run[mi];
#pragma unroll
      for (int ni = 0; ni < 4; ++ni)
#pragma unroll
        for (int j = 0; j < 4; ++j)
          st[mi][ni][j] = __builtin_amdgcn_exp2f(st[mi][ni][j] + mneg);
      // pack P in registers (dword-level; concat quads == x32 B-fragment)
#pragma unroll
      for (int kb = 0; kb < 2; ++kb) {
        pfrag[mi][kb] = mk8(__builtin_amdgcn_cvt_pkrtz(st[mi][2 * kb][0], st[mi][2 * kb][1]),
                            __builtin_amdgcn_cvt_pkrtz(st[mi][2 * kb][2], st[mi][2 * kb][3]),
                            __builtin_amdgcn_cvt_pkrtz(st[mi][2 * kb + 1][0], st[mi][2 * kb + 1][1]),
                            __builtin_amdgcn_cvt_pkrtz(st[mi][2 * kb + 1][2], st[mi][2 * kb + 1][3]));
      }
    }

    // PV + l-row: full-rate x32 MFMAs, P straight from registers
    __builtin_amdgcn_s_setprio(1);
#pragma unroll
    for (int mi = 0; mi < 2; ++mi) {
#pragma unroll
      for (int di = 0; di < 4; ++di) {
        oacc[mi][di] = __builtin_amdgcn_mfma_f32_16x16x32_f16(vf[di][0], pfrag[mi][0], oacc[mi][di], 0, 0, 0);
        oacc[mi][di] = __builtin_amdgcn_mfma_f32_16x16x32_f16(vf[di][1], pfrag[mi][1], oacc[mi][di], 0, 0, 0);
      }
      l_acc[mi] = __builtin_amdgcn_mfma_f32_16x16x32_f16(ones, pfrag[mi][0], l_acc[mi], 0, 0, 0);
      l_acc[mi] = __builtin_amdgcn_mfma_f32_16x16x32_f16(ones, pfrag[mi][1], l_acc[mi], 0, 0, 0);
    }
    __builtin_amdgcn_s_setprio(0);

    mw[0][0] = mwn[0][0]; mw[0][1] = mwn[0][1];
    mw[1][0] = mwn[1][0]; mw[1][1] = mwn[1][1];
    __syncthreads();
  };

  for (int tt = 0; tt < SS; tt += 128) {  // unroll-2: compile-time buffers
    TILE(0, tt);
    TILE(1, tt + 64);
  }

  // epilogue: /= (l * sqrt(64)); lane owns q = mi*16+l15, d = di*16+l4*4+j
#pragma unroll
  for (int mi = 0; mi < 2; ++mi) {
    float inv = 1.f / (l_acc[mi][0] * 8.f);
    size_t rowb = ((size_t)b_ * SS + (qrow0 + mi * 16 + l15)) * EE + hh * DH;
#pragma unroll
    for (int di = 0; di < 4; ++di) {
      half4v w;
#pragma unroll
      for (int j = 0; j < 4; ++j) w[j] = (h16)(oacc[mi][di][j] * inv);
      *reinterpret_cast<half4v*>(&ah[rowb + di * 16 + l4 * 4]) = w;
    }
  }
}

// ------- output projection GEMM: 128x128, BK=64, dbuf, XCD-swizzled -------
__global__ __launch_bounds__(256) void mha_oproj(
    const h16* __restrict__ A, const h16* __restrict__ Wot,
    const float* __restrict__ bo, float* __restrict__ out) {
  __shared__ __align__(16) h16 As[2][PTM * PBK];
  __shared__ __align__(16) h16 Bs[2][PTN * PBK];
  int tid = threadIdx.x, lane = tid & 63, wid = tid >> 6;
  int l15 = lane & 15, l4 = lane >> 4;
  int wr = wid >> 1, wc = wid & 1;
  int bid = blockIdx.y * 8 + blockIdx.x;
  int swz = (bid & 7) * 64 + (bid >> 3);
  int mbase = (swz >> 3) * PTM;
  int nbase = (swz & 7) * PTN;
  const f32x4 fz = {0.f, 0.f, 0.f, 0.f};
  f32x4 acc[4][4];
#pragma unroll
  for (int i = 0; i < 4; ++i)
#pragma unroll
    for (int j = 0; j < 4; ++j) acc[i][j] = fz;

  int r_loc = lane >> 3, ch = lane & 7;

  auto STAGE = [&](int buf, int kt) {
#pragma unroll
    for (int c = 0; c < 4; ++c) {
      int row = c * 32 + wid * 8 + r_loc;
      int sc_ = ch ^ (row & 7);
      gload_lds16(&A[(size_t)(mbase + row) * EE + kt + sc_ * 8], &As[buf][(c * 32 + wid * 8) * PBK]);
      gload_lds16(&Wot[(size_t)(nbase + row) * EE + kt + sc_ * 8], &Bs[buf][(c * 32 + wid * 8) * PBK]);
    }
  };

  STAGE(0, 0);
  __syncthreads();
  int cur = 0;

  for (int kt = 0; kt < EE; kt += PBK) {
    if (kt + PBK < EE) STAGE(cur ^ 1, kt + PBK);

    half8 a[2][4], b[2][4];
#pragma unroll
    for (int i = 0; i < 4; ++i) {
      int ra = wr * 64 + i * 16 + l15;
      int rb = wc * 64 + i * 16 + l15;
#pragma unroll
      for (int kk = 0; kk < 2; ++kk) {
        a[kk][i] = *reinterpret_cast<const half8*>(&As[cur][ra * PBK + ((kk * 4 + l4) ^ (ra & 7)) * 8]);
        b[kk][i] = *reinterpret_cast<const half8*>(&Bs[cur][rb * PBK + ((kk * 4 + l4) ^ (rb & 7)) * 8]);
      }
    }
#pragma unroll
    for (int kk = 0; kk < 2; ++kk)
#pragma unroll
      for (int mi = 0; mi < 4; ++mi)
#pragma unroll
        for (int ni = 0; ni < 4; ++ni)
          acc[mi][ni] = __builtin_amdgcn_mfma_f32_16x16x32_f16(b[kk][ni], a[kk][mi], acc[mi][ni], 0, 0, 0);

    __syncthreads();
    cur ^= 1;
  }
  // acc[mi][ni]: row = n-sub (l4*4+j), col = m-sub (l15) -> float4 stores
#pragma unroll
  for (int mi = 0; mi < 4; ++mi) {
    int m = mbase + wr * 64 + mi * 16 + l15;
#pragma unroll
    for (int ni = 0; ni < 4; ++ni) {
      int n0 = nbase + wc * 64 + ni * 16 + l4 * 4;
      float4 b4 = *reinterpret_cast<const float4*>(&bo[n0]);
      float4 w;
      w.x = acc[mi][ni][0] + b4.x;
      w.y = acc[mi][ni][1] + b4.y;
      w.z = acc[mi][ni][2] + b4.z;
      w.w = acc[mi][ni][3] + b4.w;
      *reinterpret_cast<float4*>(&out[(size_t)m * EE + n0]) = w;
    }
  }
}

extern "C" void kernel_launch(void* const* d_in, const int* in_sizes, int n_in,
                              void* d_out, int out_size, void* d_ws, size_t ws_size,
                              hipStream_t stream) {
  const float* query = (const float*)d_in[0];
  const float* key_ = (const float*)d_in[1];
  const float* value = (const float*)d_in[2];
  const int* mask = (const int*)d_in[3];
  const float* Wq = (const float*)d_in[4];
  const float* bq = (const float*)d_in[5];
  const float* Wk = (const float*)d_in[6];
  const float* bk = (const float*)d_in[7];
  const float* Wv = (const float*)d_in[8];
  const float* bv = (const float*)d_in[9];
  const float* Wo = (const float*)d_in[10];
  const float* bo = (const float*)d_in[11];
  float* out = (float*)d_out;

  const size_t MH = 1u << 20;                  // halves per 1024x1024 weight
  const size_t QH = (size_t)BB * HH * SS * DH; // 8388608 halves
  h16* wqt = (h16*)d_ws;
  h16* wkt = wqt + MH;
  h16* wvt = wkt + MH;
  h16* wot = wvt + MH;
  h16* qh = wot + MH;
  h16* kh = qh + QH;
  h16* vh = kh + QH;
  h16* ah = vh + QH;
  unsigned* maskw = (unsigned*)(ah + QH);

  // f16 input scratch: xq aliases the ah slot (dead before attn writes ah);
  // xk/xv live inside d_out (exactly 2*QH halves; dead until oproj overwrites).
  h16* xq = ah;
  h16* xk = (h16*)d_out;
  h16* xv = xk + QH;

  mha_prep<<<65536 + 12288 + 4096, 256, 0, stream>>>(
      mask, maskw, query, key_, value, xq, xk, xv,
      Wq, Wk, Wv, Wo, wqt, wkt, wvt, wot);
  mha_proj<<<dim3(EE / PTN, (BB * SS) / PTM, 3), 256, 0, stream>>>(
      xq, xk, xv, wqt, wkt, wvt, bq, bk, bv, qh, kh, vh);
  mha_attn<<<dim3(SS / 128, BB * HH), 256, 0, stream>>>(qh, kh, vh, maskw, ah);
  mha_oproj<<<dim3(EE / PTN, (BB * SS) / PTM), 256, 0, stream>>>(ah, wot, bo, out);
}

// Round 17
// 267.554 us; speedup vs baseline: 1.0531x; 1.0059x over previous
//
#include <hip/hip_runtime.h>

typedef _Float16 h16;
typedef h16 half8 __attribute__((ext_vector_type(8)));
typedef h16 half4v __attribute__((ext_vector_type(4)));
typedef __fp16 fp16x2 __attribute__((ext_vector_type(2)));  // cvt_pkrtz return type
typedef float f32x4 __attribute__((ext_vector_type(4)));

#define BB 4
#define SS 2048
#define EE 1024
#define HH 16
#define DH 64

__device__ __forceinline__ void gload_lds16(const void* g, void* l) {
  __builtin_amdgcn_global_load_lds((const __attribute__((address_space(1))) void*)g,
                                   (__attribute__((address_space(3))) void*)l, 16, 0, 0);
}

// assemble 4 packed half2 dwords (cvt_pkrtz results) into a half8 fragment
__device__ __forceinline__ half8 mk8(fp16x2 a, fp16x2 b, fp16x2 c, fp16x2 d) {
  union { fp16x2 p[4]; half8 v; } u;
  u.p[0] = a; u.p[1] = b; u.p[2] = c; u.p[3] = d;
  return u.v;
}

// ---- merged prep: mask pack (65536 blocks) + fp32->f16 cvt (12288) +
// weight transpose (4096). Branch is uniform per block. ----
__global__ __launch_bounds__(256) void mha_prep(
    const int* __restrict__ mask, unsigned* __restrict__ maskw,
    const float* __restrict__ q, const float* __restrict__ k, const float* __restrict__ v,
    h16* __restrict__ xq, h16* __restrict__ xk, h16* __restrict__ xv,
    const float* __restrict__ w0, const float* __restrict__ w1,
    const float* __restrict__ w2, const float* __restrict__ w3,
    h16* __restrict__ o0, h16* __restrict__ o1, h16* __restrict__ o2, h16* __restrict__ o3) {
  __shared__ float t[32][33];
  int bid = blockIdx.x;
  int tid = threadIdx.x;
  if (bid < 65536) {
    // mask pack: int32 -> bitmask
    int gid = bid * 256 + tid;
    unsigned long long bal = __ballot(mask[gid] != 0);
    int lane = tid & 63;
    if (lane == 0) maskw[gid >> 5] = (unsigned)bal;
    else if (lane == 32) maskw[gid >> 5] = (unsigned)(bal >> 32);
  } else if (bid < 65536 + 12288) {
    // fp32 -> fp16 bulk convert (query/key/value)
    int idx = bid - 65536;
    int z = idx >> 12;          // / 4096
    int xb = idx & 4095;
    const float* s = z == 0 ? q : z == 1 ? k : v;
    h16* d = z == 0 ? xq : z == 1 ? xk : xv;
    size_t i = ((size_t)xb * 256 + tid) * 8;
    float4 a = *reinterpret_cast<const float4*>(&s[i]);
    float4 b = *reinterpret_cast<const float4*>(&s[i + 4]);
    half8 h;
    h[0] = (h16)a.x; h[1] = (h16)a.y; h[2] = (h16)a.z; h[3] = (h16)a.w;
    h[4] = (h16)b.x; h[5] = (h16)b.y; h[6] = (h16)b.z; h[7] = (h16)b.w;
    *reinterpret_cast<half8*>(&d[i]) = h;
  } else {
    // weight transpose + fp32->fp16
    int idx = bid - (65536 + 12288);
    int z = idx >> 10;          // / 1024
    int rem = idx & 1023;
    const float* src = z == 0 ? w0 : z == 1 ? w1 : z == 2 ? w2 : w3;
    h16* dst = z == 0 ? o0 : z == 1 ? o1 : z == 2 ? o2 : o3;
    int x = tid & 31, y = tid >> 5;         // (32, 8) thread layout
    int bx = (rem & 31) * 32, by = (rem >> 5) * 32;
#pragma unroll
    for (int i = 0; i < 4; ++i)
      t[y + i * 8][x] = src[(size_t)(by + y + i * 8) * EE + bx + x];
    __syncthreads();
#pragma unroll
    for (int i = 0; i < 4; ++i)
      dst[(size_t)(bx + y + i * 8) * EE + by + x] = (h16)t[x][y + i * 8];
  }
}

// ------- QKV projection GEMM: 128x128, BK=64, dbuf, XCD-swizzled -------
#define PTM 128
#define PTN 128
#define PBK 64

__global__ __launch_bounds__(256) void mha_proj(
    const h16* __restrict__ Xq, const h16* __restrict__ Xk, const h16* __restrict__ Xv,
    const h16* __restrict__ Wqt, const h16* __restrict__ Wkt, const h16* __restrict__ Wvt,
    const float* __restrict__ bq, const float* __restrict__ bk, const float* __restrict__ bv,
    h16* __restrict__ Oq, h16* __restrict__ Ok, h16* __restrict__ Ov) {
  int z = blockIdx.z;
  const h16* X = z == 0 ? Xq : z == 1 ? Xk : Xv;
  const h16* Wt = z == 0 ? Wqt : z == 1 ? Wkt : Wvt;
  const float* bias = z == 0 ? bq : z == 1 ? bk : bv;
  h16* out = z == 0 ? Oq : z == 1 ? Ok : Ov;

  __shared__ __align__(16) h16 As[2][PTM * PBK];
  __shared__ __align__(16) h16 Bs[2][PTN * PBK];

  int tid = threadIdx.x;
  int lane = tid & 63, wid = tid >> 6;
  int l15 = lane & 15, l4 = lane >> 4;
  int wr = wid >> 1, wc = wid & 1;
  // T1 XCD swizzle (bijective: 512 % 8 == 0)
  int bid = blockIdx.y * 8 + blockIdx.x;
  int swz = (bid & 7) * 64 + (bid >> 3);
  int mbase = (swz >> 3) * PTM;
  int nbase = (swz & 7) * PTN;

  const f32x4 fz = {0.f, 0.f, 0.f, 0.f};
  f32x4 acc[4][4];
#pragma unroll
  for (int i = 0; i < 4; ++i)
#pragma unroll
    for (int j = 0; j < 4; ++j) acc[i][j] = fz;

  int r_loc = lane >> 3;   // 0..7 within the wave's 8-row slab
  int ch = lane & 7;       // physical 16B chunk within the 128B row

  auto STAGE = [&](int buf, int kt) {
#pragma unroll
    for (int c = 0; c < 4; ++c) {
      int row = c * 32 + wid * 8 + r_loc;
      int sc_ = ch ^ (row & 7);  // chunk-XOR swizzle via per-lane source addr
      gload_lds16(&X[(size_t)(mbase + row) * EE + kt + sc_ * 8], &As[buf][(c * 32 + wid * 8) * PBK]);
      gload_lds16(&Wt[(size_t)(nbase + row) * EE + kt + sc_ * 8], &Bs[buf][(c * 32 + wid * 8) * PBK]);
    }
  };

  STAGE(0, 0);
  __syncthreads();
  int cur = 0;

  for (int kt = 0; kt < EE; kt += PBK) {
    if (kt + PBK < EE) STAGE(cur ^ 1, kt + PBK);  // prefetch next K-tile

    half8 a[2][4], b[2][4];
#pragma unroll
    for (int i = 0; i < 4; ++i) {
      int ra = wr * 64 + i * 16 + l15;
      int rb = wc * 64 + i * 16 + l15;
#pragma unroll
      for (int kk = 0; kk < 2; ++kk) {
        a[kk][i] = *reinterpret_cast<const half8*>(&As[cur][ra * PBK + ((kk * 4 + l4) ^ (ra & 7)) * 8]);
        b[kk][i] = *reinterpret_cast<const half8*>(&Bs[cur][rb * PBK + ((kk * 4 + l4) ^ (rb & 7)) * 8]);
      }
    }
#pragma unroll
    for (int kk = 0; kk < 2; ++kk)
#pragma unroll
      for (int mi = 0; mi < 4; ++mi)
#pragma unroll
        for (int ni = 0; ni < 4; ++ni)
          acc[mi][ni] = __builtin_amdgcn_mfma_f32_16x16x32_f16(b[kk][ni], a[kk][mi], acc[mi][ni], 0, 0, 0);

    __syncthreads();  // drains prefetch after compute; swaps buffers
    cur ^= 1;
  }

  // acc[mi][ni]: row = n-sub (l4*4+j), col = m-sub (l15).
  const float qscale = (z == 0) ? 1.44269504088896f : 1.0f;
#pragma unroll
  for (int mi = 0; mi < 4; ++mi) {
    int m = mbase + wr * 64 + mi * 16 + l15;
    int b_ = m >> 11, s = m & 2047;
#pragma unroll
    for (int ni = 0; ni < 4; ++ni) {
      int n0 = nbase + wc * 64 + ni * 16 + l4 * 4;
      int h = n0 >> 6, d0 = n0 & 63;
      float4 b4 = *reinterpret_cast<const float4*>(&bias[n0]);
      if (z != 2) {
        half4v w;
        w[0] = (h16)((acc[mi][ni][0] + b4.x) * qscale);
        w[1] = (h16)((acc[mi][ni][1] + b4.y) * qscale);
        w[2] = (h16)((acc[mi][ni][2] + b4.z) * qscale);
        w[3] = (h16)((acc[mi][ni][3] + b4.w) * qscale);
        *reinterpret_cast<half4v*>(&out[(((size_t)(b_ * HH + h)) * SS + s) * DH + d0]) = w;  // (B,H,S,D)
      } else {
#pragma unroll
        for (int j = 0; j < 4; ++j)  // V^T (B,H,D,S): lanes coalesced along s
          out[(((size_t)(b_ * HH + h)) * DH + d0 + j) * SS + s] = (h16)(acc[mi][ni][j] + b4[j]);
      }
    }
  }
}

// ---------------- flash attention ----------------
// R15 structure with s_setprio REMOVED (T5 A/B: setprio is null-to-negative
// on barrier-lockstep schedules per m190; our 4 waves re-converge at a
// __syncthreads every tile, so the hint can only distort arbitration).
__global__ __launch_bounds__(256) void mha_attn(
    const h16* __restrict__ qh, const h16* __restrict__ kh, const h16* __restrict__ vh,
    const unsigned* __restrict__ maskw, h16* __restrict__ ah) {
  __shared__ __align__(16) h16 Ks[2][64 * 64];
  __shared__ __align__(16) h16 Vs[2][64 * 64];

  int bh = blockIdx.y;
  int b_ = bh >> 4, hh = bh & 15;
  int tid = threadIdx.x, lane = tid & 63, wid = tid >> 6;
  int l15 = lane & 15, l4 = lane >> 4;

  const h16* Qb = qh + (size_t)bh * SS * DH;
  const h16* Kb = kh + (size_t)bh * SS * DH;
  const h16* Vb = vh + (size_t)bh * DH * SS;
  int qrow0 = blockIdx.x * 128 + wid * 32;

  // Q fragments (B-operand of 16x16x32): lane holds Q[q = l15][k = l4*8..]
  half8 qf[2][2];
#pragma unroll
  for (int mi = 0; mi < 2; ++mi)
#pragma unroll
    for (int kk = 0; kk < 2; ++kk)
      qf[mi][kk] = *reinterpret_cast<const half8*>(&Qb[(size_t)(qrow0 + mi * 16 + l15) * DH + kk * 32 + l4 * 8]);

  half8 ones;
#pragma unroll
  for (int e = 0; e < 8; ++e) ones[e] = (h16)1.0f;

  float m_run[2] = {-1e30f, -1e30f};
  f32x4 l_acc[2];
  f32x4 oacc[2][4];
  const f32x4 fz = {0.f, 0.f, 0.f, 0.f};
#pragma unroll
  for (int mi = 0; mi < 2; ++mi) {
    l_acc[mi] = fz;
#pragma unroll
    for (int di = 0; di < 4; ++di) oacc[mi][di] = fz;
  }

  const unsigned* mwb = maskw + ((size_t)b_ * SS + qrow0) * 64;
  const unsigned* mrow0 = mwb + l15 * 64;
  const unsigned* mrow1 = mwb + (16 + l15) * 64;

  int srow = wid * 16 + (lane >> 3);   // physical LDS row this lane stages
  int schunk = lane & 7;
  int sh0 = l4 * 8;  // mask bit base: logical t = 8*l4 + 4*(ni&1) + j

  // staging sources (K rows permuted; XOR-swizzled chunks)
  int rp0 = srow, rp1 = srow + 8;
  int rl0 = (rp0 & 32) + ((rp0 >> 2) & 3) * 8 + ((rp0 >> 4) & 1) * 4 + (rp0 & 3);
  int rl1 = (rp1 & 32) + ((rp1 >> 2) & 3) * 8 + ((rp1 >> 4) & 1) * 4 + (rp1 & 3);
  int gk0 = schunk ^ (rp0 & 7), gk1 = schunk ^ (rp1 & 7);
  const h16* kp0 = Kb + (size_t)rl0 * DH + gk0 * 8;
  const h16* kp1 = Kb + (size_t)rl1 * DH + gk1 * 8;
  const h16* vp0 = Vb + (size_t)rp0 * SS + gk0 * 8;
  const h16* vp1 = Vb + (size_t)rp1 * SS + gk1 * 8;

  // collapsed LDS read offsets: K and V share them (off0: kb=0, off1: kb=1)
  int sw = l15 & 7;
  int off0 = l15 * 64 + (l4 ^ sw) * 8;
  int off1 = l15 * 64 + ((l4 + 4) ^ sw) * 8;

  // prologue: stage tile 0 + its mask words
  gload_lds16(kp0, &Ks[0][wid * 1024]);
  gload_lds16(vp0, &Vs[0][wid * 1024]);
  gload_lds16(kp1, &Ks[0][wid * 1024 + 512]);
  gload_lds16(vp1, &Vs[0][wid * 1024 + 512]);
  unsigned mw[2][2];
  mw[0][0] = mrow0[0];
  mw[0][1] = mrow0[1];
  mw[1][0] = mrow1[0];
  mw[1][1] = mrow1[1];
  __syncthreads();

  // Masked logits forced to NEG before the max so m tracks the UNMASKED max;
  // exp2(-1e5 - m) == 0 exactly -> masked p contribute 0 to PV and l.
  const unsigned negb = __float_as_uint(-1e5f);

  auto TILE = [&](int itC, int tt) {
    const int itP = itC ^ 1;
    // prefetch next tile (double buffer) + next mask words
    unsigned mwn[2][2] = {{0u, 0u}, {0u, 0u}};
    if (tt + 64 < SS) {
      size_t ko = (size_t)(tt + 64) * DH;
      gload_lds16(kp0 + ko, &Ks[itP][wid * 1024]);
      gload_lds16(vp0 + tt + 64, &Vs[itP][wid * 1024]);
      gload_lds16(kp1 + ko, &Ks[itP][wid * 1024 + 512]);
      gload_lds16(vp1 + tt + 64, &Vs[itP][wid * 1024 + 512]);
      int tw = (tt + 64) >> 5;
      mwn[0][0] = mrow0[tw];
      mwn[0][1] = mrow0[tw + 1];
      mwn[1][0] = mrow1[tw];
      mwn[1][1] = mrow1[tw + 1];
    }

    // QK^T, swapped operands: st[mi][ni] rows = PHYSICAL t-rows, col = q
    half8 kf[4][2];
#pragma unroll
    for (int ni = 0; ni < 4; ++ni) {
      kf[ni][0] = *reinterpret_cast<const half8*>(&Ks[itC][off0 + ni * 1024]);
      kf[ni][1] = *reinterpret_cast<const half8*>(&Ks[itC][off1 + ni * 1024]);
    }
    f32x4 st[2][4];
#pragma unroll
    for (int mi = 0; mi < 2; ++mi)
#pragma unroll
      for (int ni = 0; ni < 4; ++ni) {
        f32x4 t_ = fz;
        t_ = __builtin_amdgcn_mfma_f32_16x16x32_f16(kf[ni][0], qf[mi][0], t_, 0, 0, 0);
        t_ = __builtin_amdgcn_mfma_f32_16x16x32_f16(kf[ni][1], qf[mi][1], t_, 0, 0, 0);
        st[mi][ni] = t_;
      }

    // V fragments (A-operand of x32): V[d=di*16+l15][t=32kb+l4*8+e]
    half8 vf[4][2];
#pragma unroll
    for (int di = 0; di < 4; ++di) {
      vf[di][0] = *reinterpret_cast<const half8*>(&Vs[itC][off0 + di * 1024]);
      vf[di][1] = *reinterpret_cast<const half8*>(&Vs[itC][off1 + di * 1024]);
    }

    // mask BEFORE max: logical t = 32*(ni>>1) + 8*l4 + 4*(ni&1) + j
#pragma unroll
    for (int mi = 0; mi < 2; ++mi) {
#pragma unroll
      for (int ni = 0; ni < 4; ++ni) {
        unsigned m4 = mw[mi][ni >> 1] >> (sh0 + 4 * (ni & 1));
#pragma unroll
        for (int j = 0; j < 4; ++j) {
          unsigned sel = (unsigned)(((int)(m4 << (31 - j))) >> 31);  // 0 or ~0
          st[mi][ni][j] = __uint_as_float((~sel & __float_as_uint(st[mi][ni][j])) | (sel & negb));
        }
      }
    }

    // online softmax, log2 domain
    half8 pfrag[2][2];
#pragma unroll
    for (int mi = 0; mi < 2; ++mi) {
      float t0 = fmaxf(fmaxf(st[mi][0][0], st[mi][0][1]), st[mi][0][2]);
      float t1 = fmaxf(fmaxf(st[mi][0][3], st[mi][1][0]), st[mi][1][1]);
      float t2 = fmaxf(fmaxf(st[mi][1][2], st[mi][1][3]), st[mi][2][0]);
      float t3 = fmaxf(fmaxf(st[mi][2][1], st[mi][2][2]), st[mi][2][3]);
      float t4 = fmaxf(fmaxf(st[mi][3][0], st[mi][3][1]), st[mi][3][2]);
      float tmax = fmaxf(fmaxf(fmaxf(t0, t1), fmaxf(t2, t3)), fmaxf(t4, st[mi][3][3]));
      tmax = fmaxf(tmax, __shfl_xor(tmax, 16));
      tmax = fmaxf(tmax, __shfl_xor(tmax, 32));
      // T13 defer-max: rescale only when max grew by > 8 (2^8 headroom in f16)
      if (!__all(tmax - m_run[mi] <= 8.0f)) {
        float mnew = fmaxf(m_run[mi], tmax);
        float sc = __builtin_amdgcn_exp2f(m_run[mi] - mnew);
        l_acc[mi][0] *= sc;  // only component 0 is read at the end
#pragma unroll
        for (int di = 0; di < 4; ++di) oacc[mi][di] *= sc;
        m_run[mi] = mnew;
      }
      float mneg = -m_run[mi];
#pragma unroll
      for (int ni = 0; ni < 4; ++ni)
#pragma unroll
        for (int j = 0; j < 4; ++j)
          st[mi][ni][j] = __builtin_amdgcn_exp2f(st[mi][ni][j] + mneg);
      // pack P in registers (dword-level; concat quads == x32 B-fragment)
#pragma unroll
      for (int kb = 0; kb < 2; ++kb) {
        pfrag[mi][kb] = mk8(__builtin_amdgcn_cvt_pkrtz(st[mi][2 * kb][0], st[mi][2 * kb][1]),
                            __builtin_amdgcn_cvt_pkrtz(st[mi][2 * kb][2], st[mi][2 * kb][3]),
                            __builtin_amdgcn_cvt_pkrtz(st[mi][2 * kb + 1][0], st[mi][2 * kb + 1][1]),
                            __builtin_amdgcn_cvt_pkrtz(st[mi][2 * kb + 1][2], st[mi][2 * kb + 1][3]));
      }
    }

    // PV + l-row: full-rate x32 MFMAs, P straight from registers
#pragma unroll
    for (int mi = 0; mi < 2; ++mi) {
#pragma unroll
      for (int di = 0; di < 4; ++di) {
        oacc[mi][di] = __builtin_amdgcn_mfma_f32_16x16x32_f16(vf[di][0], pfrag[mi][0], oacc[mi][di], 0, 0, 0);
        oacc[mi][di] = __builtin_amdgcn_mfma_f32_16x16x32_f16(vf[di][1], pfrag[mi][1], oacc[mi][di], 0, 0, 0);
      }
      l_acc[mi] = __builtin_amdgcn_mfma_f32_16x16x32_f16(ones, pfrag[mi][0], l_acc[mi], 0, 0, 0);
      l_acc[mi] = __builtin_amdgcn_mfma_f32_16x16x32_f16(ones, pfrag[mi][1], l_acc[mi], 0, 0, 0);
    }

    mw[0][0] = mwn[0][0]; mw[0][1] = mwn[0][1];
    mw[1][0] = mwn[1][0]; mw[1][1] = mwn[1][1];
    __syncthreads();
  };

  for (int tt = 0; tt < SS; tt += 128) {  // unroll-2: compile-time buffers
    TILE(0, tt);
    TILE(1, tt + 64);
  }

  // epilogue: /= (l * sqrt(64)); lane owns q = mi*16+l15, d = di*16+l4*4+j
#pragma unroll
  for (int mi = 0; mi < 2; ++mi) {
    float inv = 1.f / (l_acc[mi][0] * 8.f);
    size_t rowb = ((size_t)b_ * SS + (qrow0 + mi * 16 + l15)) * EE + hh * DH;
#pragma unroll
    for (int di = 0; di < 4; ++di) {
      half4v w;
#pragma unroll
      for (int j = 0; j < 4; ++j) w[j] = (h16)(oacc[mi][di][j] * inv);
      *reinterpret_cast<half4v*>(&ah[rowb + di * 16 + l4 * 4]) = w;
    }
  }
}

// ------- output projection GEMM: 128x128, BK=64, dbuf, XCD-swizzled -------
__global__ __launch_bounds__(256) void mha_oproj(
    const h16* __restrict__ A, const h16* __restrict__ Wot,
    const float* __restrict__ bo, float* __restrict__ out) {
  __shared__ __align__(16) h16 As[2][PTM * PBK];
  __shared__ __align__(16) h16 Bs[2][PTN * PBK];
  int tid = threadIdx.x, lane = tid & 63, wid = tid >> 6;
  int l15 = lane & 15, l4 = lane >> 4;
  int wr = wid >> 1, wc = wid & 1;
  int bid = blockIdx.y * 8 + blockIdx.x;
  int swz = (bid & 7) * 64 + (bid >> 3);
  int mbase = (swz >> 3) * PTM;
  int nbase = (swz & 7) * PTN;
  const f32x4 fz = {0.f, 0.f, 0.f, 0.f};
  f32x4 acc[4][4];
#pragma unroll
  for (int i = 0; i < 4; ++i)
#pragma unroll
    for (int j = 0; j < 4; ++j) acc[i][j] = fz;

  int r_loc = lane >> 3, ch = lane & 7;

  auto STAGE = [&](int buf, int kt) {
#pragma unroll
    for (int c = 0; c < 4; ++c) {
      int row = c * 32 + wid * 8 + r_loc;
      int sc_ = ch ^ (row & 7);
      gload_lds16(&A[(size_t)(mbase + row) * EE + kt + sc_ * 8], &As[buf][(c * 32 + wid * 8) * PBK]);
      gload_lds16(&Wot[(size_t)(nbase + row) * EE + kt + sc_ * 8], &Bs[buf][(c * 32 + wid * 8) * PBK]);
    }
  };

  STAGE(0, 0);
  __syncthreads();
  int cur = 0;

  for (int kt = 0; kt < EE; kt += PBK) {
    if (kt + PBK < EE) STAGE(cur ^ 1, kt + PBK);

    half8 a[2][4], b[2][4];
#pragma unroll
    for (int i = 0; i < 4; ++i) {
      int ra = wr * 64 + i * 16 + l15;
      int rb = wc * 64 + i * 16 + l15;
#pragma unroll
      for (int kk = 0; kk < 2; ++kk) {
        a[kk][i] = *reinterpret_cast<const half8*>(&As[cur][ra * PBK + ((kk * 4 + l4) ^ (ra & 7)) * 8]);
        b[kk][i] = *reinterpret_cast<const half8*>(&Bs[cur][rb * PBK + ((kk * 4 + l4) ^ (rb & 7)) * 8]);
      }
    }
#pragma unroll
    for (int kk = 0; kk < 2; ++kk)
#pragma unroll
      for (int mi = 0; mi < 4; ++mi)
#pragma unroll
        for (int ni = 0; ni < 4; ++ni)
          acc[mi][ni] = __builtin_amdgcn_mfma_f32_16x16x32_f16(b[kk][ni], a[kk][mi], acc[mi][ni], 0, 0, 0);

    __syncthreads();
    cur ^= 1;
  }
  // acc[mi][ni]: row = n-sub (l4*4+j), col = m-sub (l15) -> float4 stores
#pragma unroll
  for (int mi = 0; mi < 4; ++mi) {
    int m = mbase + wr * 64 + mi * 16 + l15;
#pragma unroll
    for (int ni = 0; ni < 4; ++ni) {
      int n0 = nbase + wc * 64 + ni * 16 + l4 * 4;
      float4 b4 = *reinterpret_cast<const float4*>(&bo[n0]);
      float4 w;
      w.x = acc[mi][ni][0] + b4.x;
      w.y = acc[mi][ni][1] + b4.y;
      w.z = acc[mi][ni][2] + b4.z;
      w.w = acc[mi][ni][3] + b4.w;
      *reinterpret_cast<float4*>(&out[(size_t)m * EE + n0]) = w;
    }
  }
}

extern "C" void kernel_launch(void* const* d_in, const int* in_sizes, int n_in,
                              void* d_out, int out_size, void* d_ws, size_t ws_size,
                              hipStream_t stream) {
  const float* query = (const float*)d_in[0];
  const float* key_ = (const float*)d_in[1];
  const float* value = (const float*)d_in[2];
  const int* mask = (const int*)d_in[3];
  const float* Wq = (const float*)d_in[4];
  const float* bq = (const float*)d_in[5];
  const float* Wk = (const float*)d_in[6];
  const float* bk = (const float*)d_in[7];
  const float* Wv = (const float*)d_in[8];
  const float* bv = (const float*)d_in[9];
  const float* Wo = (const float*)d_in[10];
  const float* bo = (const float*)d_in[11];
  float* out = (float*)d_out;

  const size_t MH = 1u << 20;                  // halves per 1024x1024 weight
  const size_t QH = (size_t)BB * HH * SS * DH; // 8388608 halves
  h16* wqt = (h16*)d_ws;
  h16* wkt = wqt + MH;
  h16* wvt = wkt + MH;
  h16* wot = wvt + MH;
  h16* qh = wot + MH;
  h16* kh = qh + QH;
  h16* vh = kh + QH;
  h16* ah = vh + QH;
  unsigned* maskw = (unsigned*)(ah + QH);

  // f16 input scratch: xq aliases the ah slot (dead before attn writes ah);
  // xk/xv live inside d_out (exactly 2*QH halves; dead until oproj overwrites).
  h16* xq = ah;
  h16* xk = (h16*)d_out;
  h16* xv = xk + QH;

  mha_prep<<<65536 + 12288 + 4096, 256, 0, stream>>>(
      mask, maskw, query, key_, value, xq, xk, xv,
      Wq, Wk, Wv, Wo, wqt, wkt, wvt, wot);
  mha_proj<<<dim3(EE / PTN, (BB * SS) / PTM, 3), 256, 0, stream>>>(
      xq, xk, xv, wqt, wkt, wvt, bq, bk, bv, qh, kh, vh);
  mha_attn<<<dim3(SS / 128, BB * HH), 256, 0, stream>>>(qh, kh, vh, maskw, ah);
  mha_oproj<<<dim3(EE / PTN, (BB * SS) / PTM), 256, 0, stream>>>(ah, wot, bo, out);
}